// Round 5
// baseline (67.448 us; speedup 1.0000x reference)
//
#include <hip/hip_runtime.h>

namespace {
constexpr int kB = 32, kT = 30, kD = 512, kL = 196;
constexpr float kK = 2.8853900817779268f;  // 2*log2(e)

// tanh(z) = 1 - 2/(1+2^(kK z)); score e = C - 2*sum_d vw_d/(1+E*F); C cancels
// in softmax. E = 2^(kK(x+w)) (t-dep), F = 2^(kK img) (l-dep).
// Pairwise: vwi/u + vwj/v = (vwi*v + vwj*u) / (u*v)  -> 1 rcp per 2 elements.
// g[p][b][t][l], p = ds*2+dh (8 partials of 64 d each).
// Block: 128 thr = 2 waves (dh halves). Wave tile: 16t x 14l x 64d.
__global__ __launch_bounds__(128, 8) void k_score(
    const float* __restrict__ x, const float* __restrict__ w,
    const float* __restrict__ img, const float* __restrict__ vw,
    float* __restrict__ g) {
  __shared__ __align__(16) float4 E4[16 * 32];  // [tt][c4 ^ (tt&7)] 8 KB
  __shared__ __align__(16) float4 F4[14 * 32];  // [r][c4 ^ (r&7)]   7 KB
  const int lc = blockIdx.x;       // 14 l-chunks
  const int ds = blockIdx.y >> 1;  // 4 d-slices of 128
  const int th = blockIdx.y & 1;   // 2 t-halves of 16
  const int b = blockIdx.z;
  const int l0 = lc * 14, d0 = ds * 128;
  const int tid = threadIdx.x;
  // stage E = 2^(kK(x+w)) for rows th*16..th*16+15 (t>=30 -> 1.0)
#pragma unroll
  for (int k = 0; k < 4; ++k) {
    const int i = tid + k * 128;
    const int tt = i >> 5, c4 = i & 31;
    const int t = th * 16 + tt;
    float4 v = {1.f, 1.f, 1.f, 1.f};
    if (t < kT) {
      const size_t gi = ((size_t)(b * kT + t)) * kD + d0 + 4 * c4;
      const float4 xv = *(const float4*)(x + gi);
      const float4 wv = *(const float4*)(w + gi);
      v.x = __builtin_amdgcn_exp2f(kK * (xv.x + wv.x));
      v.y = __builtin_amdgcn_exp2f(kK * (xv.y + wv.y));
      v.z = __builtin_amdgcn_exp2f(kK * (xv.z + wv.z));
      v.w = __builtin_amdgcn_exp2f(kK * (xv.w + wv.w));
    }
    E4[tt * 32 + (c4 ^ (tt & 7))] = v;
  }
  // stage F = 2^(kK img) for rows l0..l0+13
#pragma unroll
  for (int k = 0; k < 4; ++k) {
    const int i = tid + k * 128;
    if (i < 448) {
      const int r = i >> 5, c4 = i & 31;
      const size_t gi = ((size_t)(b * kL + l0 + r)) * kD + d0 + 4 * c4;
      const float4 gv = *(const float4*)(img + gi);
      float4 v;
      v.x = __builtin_amdgcn_exp2f(kK * gv.x);
      v.y = __builtin_amdgcn_exp2f(kK * gv.y);
      v.z = __builtin_amdgcn_exp2f(kK * gv.z);
      v.w = __builtin_amdgcn_exp2f(kK * gv.w);
      F4[r * 32 + (c4 ^ (r & 7))] = v;
    }
  }
  __syncthreads();
  const int lane = tid & 63;
  const int tt = lane & 15, ls = lane >> 4;  // 16 t x 4 l-groups
  const int dh = __builtin_amdgcn_readfirstlane(tid >> 6);  // wave = 64-d half
  const int loff = (ls < 2) ? ls * 4 : (ls == 2 ? 8 : 11);  // {0,4,8,11}
  const int nl = (ls < 2) ? 4 : 3;                          // {4,4,3,3}
  const float* vwp = vw + d0 + dh * 64;  // uniform -> s_load
  const float4* Ep = &E4[tt * 32];
  const int sw = tt & 7;
  float acc[4] = {0.f, 0.f, 0.f, 0.f};
#pragma unroll
  for (int q = 0; q < 16; ++q) {
    const int c4 = dh * 16 + q;
    const float4 e = Ep[c4 ^ sw];
    const float4 vv = *(const float4*)(vwp + 4 * q);
#pragma unroll
    for (int j = 0; j < 4; ++j) {
      const int rr = loff + j;
      const int r = (rr <= 13) ? rr : 13;  // clamp (computed, not stored)
      const float4 f = F4[r * 32 + (c4 ^ (r & 7))];
      // pair (x,y): vv.x/u + vv.y/v = (vv.x*v + vv.y*u) * rcp(u*v)
      float u = fmaf(e.x, f.x, 1.f);
      float v2 = fmaf(e.y, f.y, 1.f);
      float t1 = u * vv.y;
      float num = fmaf(v2, vv.x, t1);
      acc[j] = fmaf(num, __builtin_amdgcn_rcpf(u * v2), acc[j]);
      // pair (z,w)
      u = fmaf(e.z, f.z, 1.f);
      v2 = fmaf(e.w, f.w, 1.f);
      t1 = u * vv.w;
      num = fmaf(v2, vv.z, t1);
      acc[j] = fmaf(num, __builtin_amdgcn_rcpf(u * v2), acc[j]);
    }
  }
  const int t = th * 16 + tt;
  if (t < kT) {
    const int p = ds * 2 + dh;
    float* gp = g + (((size_t)(p * kB + b)) * kT + t) * kL + l0 + loff;
#pragma unroll
    for (int j = 0; j < 4; ++j)
      if (j < nl) gp[j] = acc[j];
  }
}

// Merged softmax + context. Block = (dq: 8 x 64d, th: 2 x 15t, b).
// Phase 1: softmax over l for this block's 15 t rows (dup across dq).
// Phase 2: context[b][t][d] = sum_l img[b][l][d] * alpha[t][l].
__global__ __launch_bounds__(256) void k_actx(
    const float* __restrict__ img, const float* __restrict__ g,
    float* __restrict__ out) {
  __shared__ float A[16][200];  // [t_local][l], row 15 zeroed
  const int dq = blockIdx.x, th = blockIdx.y, b = blockIdx.z;
  const int d0 = dq * 64;
  const int tid = threadIdx.x;
  const int lane = tid & 63, wv = tid >> 6;
  // zero pad row 15 (read by wave 3's unused 4th accumulator)
  for (int i = tid; i < 200; i += 256) A[15][i] = 0.f;
  // phase 1: rows {4,4,4,3} per wave
  const int r0 = wv * 4, nr = (wv < 3) ? 4 : 3;
  for (int i = 0; i < nr; ++i) {
    const int tl = r0 + i, t = th * 15 + tl;
    float q0 = 0.f, q1 = 0.f, q2 = 0.f, q3 = 0.f;
#pragma unroll
    for (int p = 0; p < 8; ++p) {
      const float* gp = g + (((size_t)(p * kB + b)) * kT + t) * kL;
      q0 += gp[lane];
      q1 += gp[lane + 64];
      q2 += gp[lane + 128];
      if (lane < kL - 192) q3 += gp[lane + 192];
    }
    q0 *= kK; q1 *= kK; q2 *= kK;
    q3 = (lane < kL - 192) ? q3 * kK : __builtin_inff();
    float m = fminf(fminf(q0, q1), fminf(q2, q3));
#pragma unroll
    for (int mm = 1; mm < 64; mm <<= 1) m = fminf(m, __shfl_xor(m, mm, 64));
    const float e0 = __builtin_amdgcn_exp2f(m - q0);
    const float e1 = __builtin_amdgcn_exp2f(m - q1);
    const float e2 = __builtin_amdgcn_exp2f(m - q2);
    const float e3 = (lane < kL - 192) ? __builtin_amdgcn_exp2f(m - q3) : 0.f;
    float s = e0 + e1 + e2 + e3;
#pragma unroll
    for (int mm = 1; mm < 64; mm <<= 1) s += __shfl_xor(s, mm, 64);
    const float rs = __builtin_amdgcn_rcpf(s);
    A[tl][lane] = e0 * rs;
    A[tl][lane + 64] = e1 * rs;
    A[tl][lane + 128] = e2 * rs;
    if (lane < kL - 192) A[tl][lane + 192] = e3 * rs;
  }
  __syncthreads();
  // phase 2: thread = (d=lane, tgroup=wv); rows {4,4,4,3}
  const int t0 = wv * 4, nt = (wv < 3) ? 4 : 3;
  float acc[4] = {0.f, 0.f, 0.f, 0.f};
  const float* ip = img + ((size_t)b * kL) * kD + d0 + lane;
#pragma unroll 2
  for (int l = 0; l < kL; ++l) {
    const float v = ip[(size_t)l * kD];
    acc[0] = fmaf(v, A[t0 + 0][l], acc[0]);
    acc[1] = fmaf(v, A[t0 + 1][l], acc[1]);
    acc[2] = fmaf(v, A[t0 + 2][l], acc[2]);
    acc[3] = fmaf(v, A[t0 + 3][l], acc[3]);
  }
#pragma unroll
  for (int j = 0; j < 4; ++j) {
    if (j < nt) {
      out[((size_t)(b * kT + th * 15 + t0 + j)) * kD + d0 + lane] = acc[j];
    }
  }
}
}  // namespace

extern "C" void kernel_launch(void* const* d_in, const int* in_sizes, int n_in,
                              void* d_out, int out_size, void* d_ws, size_t ws_size,
                              hipStream_t stream) {
  const float* x = (const float*)d_in[0];
  const float* wordemb = (const float*)d_in[1];
  const float* img = (const float*)d_in[2];
  const float* vw = (const float*)d_in[3];
  // v_b (d_in[4]) cancels in the softmax along with sum(v_w) — unused by design.
  float* out = (float*)d_out;
  float* g = (float*)d_ws;  // 8*32*30*196 floats = 6.02 MB
  hipLaunchKernelGGL(k_score, dim3(14, 8, kB), dim3(128), 0, stream, x,
                     wordemb, img, vw, g);
  hipLaunchKernelGGL(k_actx, dim3(8, 2, kB), dim3(256), 0, stream, img, g,
                     out);
}

// Round 6
// 50.765 us; speedup vs baseline: 1.3286x; 1.3286x over previous
//
#include <hip/hip_runtime.h>

namespace {
constexpr int kB = 32, kT = 30, kD = 512, kL = 196;
constexpr float kK = 2.8853900817779268f;  // 2*log2(e)
constexpr size_t kEgN = (size_t)kB * kT * kD;        // 491,520
constexpr size_t kFN = (size_t)kB * (kD / 4) * kL * 4;  // 3,211,264
constexpr size_t kGsz = (size_t)kB * kT * kL;        // 188,160 (per d-half)

// Eg[b][t][d] = 2^(kK*(x+w))
__global__ __launch_bounds__(256) void k_prep_e(const float* __restrict__ x,
                                                const float* __restrict__ w,
                                                float* __restrict__ Eg) {
  const float4* x4 = (const float4*)x;
  const float4* w4 = (const float4*)w;
  float4* e4 = (float4*)Eg;
  const int n4 = (int)(kEgN / 4);
  for (int i = blockIdx.x * 256 + threadIdx.x; i < n4; i += gridDim.x * 256) {
    const float4 a = x4[i], b = w4[i];
    float4 r;
    r.x = __builtin_amdgcn_exp2f(kK * (a.x + b.x));
    r.y = __builtin_amdgcn_exp2f(kK * (a.y + b.y));
    r.z = __builtin_amdgcn_exp2f(kK * (a.z + b.z));
    r.w = __builtin_amdgcn_exp2f(kK * (a.w + b.w));
    e4[i] = r;
  }
}

// imgF4[b][dq][l][j] = 2^(kK*img[b][l][4*dq+j]); dq in [0,128)
__global__ __launch_bounds__(256) void k_prep_f(const float* __restrict__ img,
                                                float* __restrict__ imgF4) {
  const int lq = blockIdx.x, b = blockIdx.y;  // 14 l per block
  const int tid = threadIdx.x;
  const int ls = tid >> 7, dq = tid & 127;
#pragma unroll
  for (int r = 0; r < 7; ++r) {
    const int l = lq * 14 + 2 * r + ls;
    const float4 v = *(const float4*)(img + ((size_t)(b * kL + l)) * kD + 4 * dq);
    float4 o;
    o.x = __builtin_amdgcn_exp2f(kK * v.x);
    o.y = __builtin_amdgcn_exp2f(kK * v.y);
    o.z = __builtin_amdgcn_exp2f(kK * v.z);
    o.w = __builtin_amdgcn_exp2f(kK * v.w);
    *(float4*)(imgF4 + (((size_t)(b * 128 + dq)) * kL + l) * 4) = o;
  }
}

// g2[dh][b][t][l] = sum over 256 d of vw_d/(1+E*F).
// Wave = (lc,tp,dh,b); lane = l. E/vw lane-invariant -> scalar loads.
// No LDS, no barriers, no cross-lane reduce.
__global__ __launch_bounds__(64) void k_scoreT(const float* __restrict__ Eg,
                                               const float* __restrict__ imgF4,
                                               const float* __restrict__ vw,
                                               float* __restrict__ g2) {
  const int lane = threadIdx.x;
  const int lc = blockIdx.x, tp = blockIdx.y;
  const int dh = blockIdx.z & 1, b = blockIdx.z >> 1;
  const int l0 = (lc < 3) ? lc * 64 : 132;  // chunk 3 overlaps 128..131 (benign dup)
  const int t = 2 * tp;
  const float* Fp =
      imgF4 + (((size_t)(b * 128 + dh * 64)) * kL + l0 + lane) * 4;
  const float* e0 = Eg + ((size_t)(b * kT + t)) * kD + dh * 256;
  const float* e1 = e0 + kD;
  const float* vp = vw + dh * 256;
  float a0 = 0.f, a1 = 0.f;
#pragma unroll 4
  for (int s = 0; s < 64; ++s) {
    const float4 f = *(const float4*)(Fp + (size_t)s * (kL * 4));
    const float4 ea = *(const float4*)(e0 + 4 * s);  // uniform -> s_load
    const float4 eb = *(const float4*)(e1 + 4 * s);  // uniform -> s_load
    const float4 vv = *(const float4*)(vp + 4 * s);  // uniform -> s_load
    // vv.x/u + vv.y/v = (vv.x*v + vv.y*u) * rcp(u*v)
    float u = fmaf(ea.x, f.x, 1.f);
    float v = fmaf(ea.y, f.y, 1.f);
    a0 = fmaf(fmaf(v, vv.x, u * vv.y), __builtin_amdgcn_rcpf(u * v), a0);
    u = fmaf(ea.z, f.z, 1.f);
    v = fmaf(ea.w, f.w, 1.f);
    a0 = fmaf(fmaf(v, vv.z, u * vv.w), __builtin_amdgcn_rcpf(u * v), a0);
    u = fmaf(eb.x, f.x, 1.f);
    v = fmaf(eb.y, f.y, 1.f);
    a1 = fmaf(fmaf(v, vv.x, u * vv.y), __builtin_amdgcn_rcpf(u * v), a1);
    u = fmaf(eb.z, f.z, 1.f);
    v = fmaf(eb.w, f.w, 1.f);
    a1 = fmaf(fmaf(v, vv.z, u * vv.w), __builtin_amdgcn_rcpf(u * v), a1);
  }
  float* gp = g2 + (size_t)dh * kGsz + ((size_t)(b * kT + t)) * kL + l0 + lane;
  gp[0] = a0;
  gp[kL] = a1;
}

// alpha[b][t][l] = softmax_l of (C - 2*g); weights ~ 2^(min(q)-q), q=kK*(g0+g1)
__global__ __launch_bounds__(512) void k_alpha(const float* __restrict__ g2,
                                               float* __restrict__ alpha) {
  const int qd = blockIdx.x, b = blockIdx.y;
  const int lane = threadIdx.x & 63, wv = threadIdx.x >> 6;
  const int t = qd * 8 + wv;
  if (t >= kT) return;
  const size_t base = ((size_t)(b * kT + t)) * kL;
  const float* g0 = g2 + base;
  const float* g1 = g2 + kGsz + base;
  float q0 = (g0[lane] + g1[lane]) * kK;
  float q1 = (g0[lane + 64] + g1[lane + 64]) * kK;
  float q2 = (g0[lane + 128] + g1[lane + 128]) * kK;
  float q3 = (lane < kL - 192) ? (g0[lane + 192] + g1[lane + 192]) * kK
                               : __builtin_inff();
  float m = fminf(fminf(q0, q1), fminf(q2, q3));
#pragma unroll
  for (int mm = 1; mm < 64; mm <<= 1) m = fminf(m, __shfl_xor(m, mm, 64));
  const float e0 = __builtin_amdgcn_exp2f(m - q0);
  const float e1 = __builtin_amdgcn_exp2f(m - q1);
  const float e2 = __builtin_amdgcn_exp2f(m - q2);
  const float e3 = (lane < kL - 192) ? __builtin_amdgcn_exp2f(m - q3) : 0.f;
  float s = e0 + e1 + e2 + e3;
#pragma unroll
  for (int mm = 1; mm < 64; mm <<= 1) s += __shfl_xor(s, mm, 64);
  const float rs = __builtin_amdgcn_rcpf(s);
  float* ab = alpha + base;
  ab[lane] = e0 * rs;
  ab[lane + 64] = e1 * rs;
  ab[lane + 128] = e2 * rs;
  if (lane < kL - 192) ab[lane + 192] = e3 * rs;
}

// context[b][t][d] = sum_l img[b][l][d]*alpha[b][t][l].
// Block = (th:5t, dh:256d, b); 4 waves each own a 49-l quarter; lane = d-quad.
// alpha via wave-uniform scalar loads; img via coalesced b128; LDS only for
// the final 4-way partial reduce.
__global__ __launch_bounds__(256) void k_ctx(const float* __restrict__ img,
                                             const float* __restrict__ alpha,
                                             float* __restrict__ out) {
  __shared__ __align__(16) float red[4][5][256];  // 20 KB
  const int th = blockIdx.x, dh = blockIdx.y, b = blockIdx.z;
  const int t0 = th * 5, d0 = dh * 256;
  const int tid = threadIdx.x;
  const int lane = tid & 63;
  const int lru = __builtin_amdgcn_readfirstlane(tid >> 6);  // wave's l-quarter
  const float* ap = alpha + ((size_t)(b * kT + t0)) * kL + lru * 49;  // uniform
  const float* ip =
      img + ((size_t)(b * kL + lru * 49)) * kD + d0 + 4 * lane;
  float4 acc[5];
#pragma unroll
  for (int j = 0; j < 5; ++j) acc[j] = {0.f, 0.f, 0.f, 0.f};
#pragma unroll 4
  for (int i = 0; i < 49; ++i) {
    const float4 v = *(const float4*)(ip + (size_t)i * kD);
    const float a0 = ap[i];
    const float a1 = ap[kL + i];
    const float a2 = ap[2 * kL + i];
    const float a3 = ap[3 * kL + i];
    const float a4 = ap[4 * kL + i];
    acc[0].x = fmaf(v.x, a0, acc[0].x); acc[0].y = fmaf(v.y, a0, acc[0].y);
    acc[0].z = fmaf(v.z, a0, acc[0].z); acc[0].w = fmaf(v.w, a0, acc[0].w);
    acc[1].x = fmaf(v.x, a1, acc[1].x); acc[1].y = fmaf(v.y, a1, acc[1].y);
    acc[1].z = fmaf(v.z, a1, acc[1].z); acc[1].w = fmaf(v.w, a1, acc[1].w);
    acc[2].x = fmaf(v.x, a2, acc[2].x); acc[2].y = fmaf(v.y, a2, acc[2].y);
    acc[2].z = fmaf(v.z, a2, acc[2].z); acc[2].w = fmaf(v.w, a2, acc[2].w);
    acc[3].x = fmaf(v.x, a3, acc[3].x); acc[3].y = fmaf(v.y, a3, acc[3].y);
    acc[3].z = fmaf(v.z, a3, acc[3].z); acc[3].w = fmaf(v.w, a3, acc[3].w);
    acc[4].x = fmaf(v.x, a4, acc[4].x); acc[4].y = fmaf(v.y, a4, acc[4].y);
    acc[4].z = fmaf(v.z, a4, acc[4].z); acc[4].w = fmaf(v.w, a4, acc[4].w);
  }
#pragma unroll
  for (int j = 0; j < 5; ++j) *(float4*)&red[lru][j][4 * lane] = acc[j];
  __syncthreads();
  // tid = d-column; sum the 4 wave partials, write out
#pragma unroll
  for (int j = 0; j < 5; ++j) {
    const float s = red[0][j][tid] + red[1][j][tid] + red[2][j][tid] +
                    red[3][j][tid];
    out[((size_t)(b * kT + t0 + j)) * kD + d0 + tid] = s;
  }
}
}  // namespace

extern "C" void kernel_launch(void* const* d_in, const int* in_sizes, int n_in,
                              void* d_out, int out_size, void* d_ws, size_t ws_size,
                              hipStream_t stream) {
  const float* x = (const float*)d_in[0];
  const float* wordemb = (const float*)d_in[1];
  const float* img = (const float*)d_in[2];
  const float* vw = (const float*)d_in[3];
  // v_b (d_in[4]) cancels in the softmax along with sum(v_w) — unused by design.
  float* out = (float*)d_out;
  float* Eg = (float*)d_ws;            // 1.97 MB
  float* imgF4 = Eg + kEgN;            // 12.8 MB
  float* g2 = imgF4 + kFN;             // 1.51 MB
  float* alpha = g2 + 2 * kGsz;        // 0.75 MB  (total ~17.1 MB)
  hipLaunchKernelGGL(k_prep_e, dim3(240), dim3(256), 0, stream, x, wordemb, Eg);
  hipLaunchKernelGGL(k_prep_f, dim3(14, kB), dim3(256), 0, stream, img, imgF4);
  hipLaunchKernelGGL(k_scoreT, dim3(4, 15, 64), dim3(64), 0, stream, Eg, imgF4,
                     vw, g2);
  hipLaunchKernelGGL(k_alpha, dim3(4, kB), dim3(512), 0, stream, g2, alpha);
  hipLaunchKernelGGL(k_ctx, dim3(6, 2, kB), dim3(256), 0, stream, img, alpha,
                     out);
}